// Round 1
// 159.903 us; speedup vs baseline: 1.1727x; 1.1727x over previous
//
#include <hip/hip_runtime.h>
#include <math.h>

// RG-LRU: B=4, T=4096, W=1024, H=8, BW=128
// Single-pass chained scan (decoupled look-back) — computes gates/scan ONCE.
#define NB 4
#define NT 4096
#define NW 1024
#define NH 8
#define CHUNK 64
#define NCH 64          // NT / CHUNK
#define STRIDE_A 136    // bf16 elems per LDS A-row: 272 B = 17*16 (16B-aligned, bank-friendly)

typedef __attribute__((ext_vector_type(8))) short short8;
typedef __attribute__((ext_vector_type(4))) float f32x4;

__device__ __forceinline__ short bf16rne(float f) {
    unsigned u = __float_as_uint(f);
    u += 0x7fffu + ((u >> 16) & 1u);      // round-to-nearest-even
    return (short)(u >> 16);
}

// ---------------- K0: convert w_in/w_a to frag-major bf16 + NaN-poison scan state ----
// dst index: ((((h*2+g)*4+ks)*8 + ntg)*64 + lane)*8 + jj
//   where i (input dim) = ks*32 + quad*8 + jj, lane = quad*16 + (j&15), ntg = j>>4
// Also poisons Ag/Hg/Hi (3 MiB = 196608 uint4) with NaN so the look-back protocol
// is self-validating per 32-bit word (no flags, no fences, graph-replay safe).
__global__ __launch_bounds__(256)
void k0_wfrag(const float* __restrict__ w_in, const float* __restrict__ w_a,
              short* __restrict__ wfH, uint4* __restrict__ poison)
{
    int idx = blockIdx.x * 256 + threadIdx.x;   // over 2*8*128*32 = 65536
    uint4 nv; nv.x = nv.y = nv.z = nv.w = 0xFFFFFFFFu;   // NaN
    poison[idx]          = nv;
    poison[idx + 65536]  = nv;
    poison[idx + 131072] = nv;

    int j4 = (idx & 31) * 4;
    int i  = (idx >> 5) & 127;
    int h  = (idx >> 12) & 7;
    int g  = idx >> 15;
    const float* w = g ? w_a : w_in;
    float4 v = *(const float4*)&w[((size_t)h * 128 + i) * 128 + j4];
    const float vf[4] = {v.x, v.y, v.z, v.w};
    const int ks = i >> 5, q = (i >> 3) & 3, jj = i & 7;
    #pragma unroll
    for (int d = 0; d < 4; ++d) {
        int j = j4 + d;
        int lane = q * 16 + (j & 15);
        int ntg = j >> 4;
        size_t dst = ((size_t)(((h * 2 + g) * 4 + ks) * 8 + ntg) * 64 + lane) * 8 + jj;
        wfH[dst] = bf16rne(vf[d]);
    }
}

// ---------------- K: MFMA gates + chunk scan + decoupled look-back + store ----------
// grid (NH, NB*NCH), block 512 (8 waves); block tile = 64 t x 128 w (one head).
// Grid linear order h + 8*(b*64+c) is monotone in c per (h,b) chain -> with in-order
// dispatch every resident block's predecessors are resident-or-retired (no deadlock).
// Per-column publications: Ag/Hg = chunk aggregate (h_out = cA*h_in + cH),
// Hi = inclusive state at end of chunk. NaN = not yet published.
__global__ __launch_bounds__(512)
void k_fused(const float* __restrict__ x, const int* __restrict__ seg,
             const float* __restrict__ a_param,
             const float* __restrict__ b_in, const float* __restrict__ b_a,
             const short* __restrict__ wfH,
             float* __restrict__ Ag, float* __restrict__ Hg,
             float* __restrict__ Hi, float* __restrict__ out)
{
    __shared__ short sA[64 * STRIDE_A];   // 17.4 KB

    const int h   = blockIdx.x;
    const int bc  = blockIdx.y;           // b*NCH + c
    const int b   = bc >> 6, c = bc & 63;
    const int tid = threadIdx.x;
    const int wave = tid >> 6, lane = tid & 63;   // wave = n-tile group (0..7)
    const int quad = lane >> 4, m = lane & 15;
    const int row0 = b * NT + c * CHUNK;          // global row into [B*T]

    // ---- stage A: x tile (64 t x 128 k) -> bf16 LDS, one conversion per element ----
    {
        const int r  = tid >> 3;           // 0..63
        const int k0 = (tid & 7) * 16;     // 0,16,..,112
        const float4* px = (const float4*)(x + (size_t)(row0 + r) * NW + h * 128 + k0);
        float4 v0 = px[0], v1 = px[1], v2 = px[2], v3 = px[3];
        const float f[16] = {v0.x, v0.y, v0.z, v0.w, v1.x, v1.y, v1.z, v1.w,
                             v2.x, v2.y, v2.z, v2.w, v3.x, v3.y, v3.z, v3.w};
        short8 s0, s1;
        #pragma unroll
        for (int j = 0; j < 8; ++j) { s0[j] = bf16rne(f[j]); s1[j] = bf16rne(f[8 + j]); }
        *(short8*)&sA[r * STRIDE_A + k0]     = s0;
        *(short8*)&sA[r * STRIDE_A + k0 + 8] = s1;
    }
    __syncthreads();

    // ---- MFMA main loop over K (A from LDS, B frags from L2-resident wfH) ----
    f32x4 acc[2][4];  // [gate][mt]
    #pragma unroll
    for (int g = 0; g < 2; ++g)
        #pragma unroll
        for (int mt = 0; mt < 4; ++mt)
            acc[g][mt] = (f32x4){0.f, 0.f, 0.f, 0.f};

    #pragma unroll
    for (int ks = 0; ks < 4; ++ks) {
        short8 ah[4];
        #pragma unroll
        for (int mt = 0; mt < 4; ++mt)
            ah[mt] = *(const short8*)&sA[(mt * 16 + m) * STRIDE_A + ks * 32 + quad * 8];
        #pragma unroll
        for (int g = 0; g < 2; ++g) {
            const size_t fo = ((size_t)(((h * 2 + g) * 4 + ks) * 8 + wave) * 64 + lane) * 8;
            short8 bh = *(const short8*)(wfH + fo);
            #pragma unroll
            for (int mt = 0; mt < 4; ++mt)
                acc[g][mt] = __builtin_amdgcn_mfma_f32_16x16x32_bf16(ah[mt], bh, acc[g][mt], 0, 0, 0);
        }
    }

    // ---- per-column parameters ----
    const int col  = wave * 16 + m;       // 0..127 within head
    const int colg = h * 128 + col;
    const float bi = b_in[colg];
    const float ba = b_a[colg];
    const float c2 = -8.0f * log1pf(expf(a_param[colg]));   // -8*softplus

    // ---- epilogue + chunk-local scan (C layout: row = quad*4+reg, col = lane&15) ----
    float cA = 1.f, cH = 0.f;             // carry across m-tiles (per column)
    float Pf[4][4], Hf[4][4];             // retained: out = Hf + Pf * h_prev
    #pragma unroll
    for (int mt = 0; mt < 4; ++mt) {
        float lP[4], lH[4];
        {
            float xv[4]; int sv[4];
            #pragma unroll
            for (int r = 0; r < 4; ++r) {
                const int rowi = row0 + mt * 16 + quad * 4 + r;
                xv[r] = x[(size_t)rowi * NW + colg];
                sv[r] = seg[rowi];
            }
            #pragma unroll
            for (int r = 0; r < 4; ++r) {
                const float zx = acc[0][mt][r] + bi;
                const float za = acc[1][mt][r] + ba;
                const float gx = __fdividef(1.f, 1.f + __expf(-zx));
                const float ga = __fdividef(1.f, 1.f + __expf(-za));
                const float a  = __expf(c2 * ga);
                const float mult = sqrtf(fmaxf(fmaf(-a, a, 1.f), 0.f));
                const float av = (sv[r] == 0) ? 0.f : a;
                const float nx = xv[r] * gx * mult;
                lP[r] = (r == 0) ? av : lP[r - 1] * av;
                lH[r] = (r == 0) ? nx : fmaf(av, lH[r - 1], nx);
            }
        }
        // cross-quad inclusive scan of quad totals
        float iA = lP[3], iH = lH[3];
        float uA = __shfl_up(iA, 16), uH = __shfl_up(iH, 16);
        if (quad >= 1) { iH = fmaf(iA, uH, iH); iA = uA * iA; }
        uA = __shfl_up(iA, 32); uH = __shfl_up(iH, 32);
        if (quad >= 2) { iH = fmaf(iA, uH, iH); iA = uA * iA; }
        // exclusive prefix for this quad
        float eA = __shfl_up(iA, 16), eH = __shfl_up(iH, 16);
        if (quad == 0) { eA = 1.f; eH = 0.f; }
        // 16-t tile total (quad 3 inclusive), broadcast per column
        const float mAt = __shfl(iA, 48 + m);
        const float mHt = __shfl(iH, 48 + m);
        // prefix = carry ∘ quad-exclusive; update carry
        const float pA = cA * eA;
        const float pH = fmaf(eA, cH, eH);
        cH = fmaf(mAt, cH, mHt);
        cA = cA * mAt;
        #pragma unroll
        for (int r = 0; r < 4; ++r) {
            Pf[mt][r] = pA * lP[r];
            Hf[mt][r] = fmaf(lP[r], pH, lH[r]);
        }
    }
    // NOTE: cA,cH (chunk totals) are replicated across quads for each (wave,m).

    // ---- decoupled look-back: quad-0 lanes own their wave's 16 columns ----
    const size_t cb0 = (size_t)(h * NB + b) * NCH * 128;   // chain base
    float hp = 0.f;                                        // state entering this chunk
    if (quad == 0) {
        const size_t oc = cb0 + (size_t)c * 128 + col;
        if (c > 0) {
            __hip_atomic_store(&Ag[oc], cA, __ATOMIC_RELAXED, __HIP_MEMORY_SCOPE_AGENT);
            __hip_atomic_store(&Hg[oc], cH, __ATOMIC_RELAXED, __HIP_MEMORY_SCOPE_AGENT);
            float accA = 1.f, accH = 0.f;
            int k = c - 1;
            for (;;) {
                const size_t o = cb0 + (size_t)k * 128 + col;
                // issue all three loads concurrently (one round trip)
                const float hv = __hip_atomic_load(&Hi[o], __ATOMIC_RELAXED, __HIP_MEMORY_SCOPE_AGENT);
                const float A_ = __hip_atomic_load(&Ag[o], __ATOMIC_RELAXED, __HIP_MEMORY_SCOPE_AGENT);
                const float H_ = __hip_atomic_load(&Hg[o], __ATOMIC_RELAXED, __HIP_MEMORY_SCOPE_AGENT);
                if (!__builtin_isnan(hv)) {            // inclusive known -> done
                    hp = fmaf(accA, hv, accH);
                    break;
                }
                if (__builtin_isnan(A_) || __builtin_isnan(H_)) {
                    __builtin_amdgcn_s_sleep(2);       // not yet published, retry
                    continue;
                }
                accH = fmaf(accA, H_, accH);           // fold aggregate, step back
                accA *= A_;
                --k;
            }
        }
        // publish inclusive state of THIS chunk ASAP (unblocks successors)
        __hip_atomic_store(&Hi[oc], fmaf(cA, hp, cH), __ATOMIC_RELAXED, __HIP_MEMORY_SCOPE_AGENT);
    }
    hp = __shfl(hp, m);   // broadcast column state from quad-0 lane m

    // ---- final stores: out = Hf + Pf * h_prev (64B sectors per quad-row) ----
    #pragma unroll
    for (int mt = 0; mt < 4; ++mt) {
        #pragma unroll
        for (int r = 0; r < 4; ++r) {
            const int rowi = row0 + mt * 16 + quad * 4 + r;
            out[(size_t)rowi * NW + colg] = fmaf(Pf[mt][r], hp, Hf[mt][r]);
        }
    }
}

extern "C" void kernel_launch(void* const* d_in, const int* in_sizes, int n_in,
                              void* d_out, int out_size, void* d_ws, size_t ws_size,
                              hipStream_t stream)
{
    (void)in_sizes; (void)n_in; (void)out_size; (void)ws_size;
    const float* x    = (const float*)d_in[0];
    const int*   seg  = (const int*)  d_in[1];
    const float* ap   = (const float*)d_in[2];
    const float* w_in = (const float*)d_in[3];
    const float* b_in = (const float*)d_in[4];
    const float* w_a  = (const float*)d_in[5];
    const float* b_a  = (const float*)d_in[6];
    float* out = (float*)d_out;

    // ws layout (~3.5 MiB): Ag/Hg/Hi (1 MiB each, NaN-poisoned by k0) + wfH (0.5 MiB)
    const size_t NTOP = (size_t)NH * NB * NCH * 128;   // 262144
    float* Ag  = (float*)d_ws;
    float* Hg  = Ag + NTOP;
    float* Hi  = Hg + NTOP;
    short* wfH = (short*)(Hi + NTOP);

    k0_wfrag<<<256, 256, 0, stream>>>(w_in, w_a, wfH, (uint4*)Ag);
    dim3 g1(NH, NB * NCH);
    k_fused<<<g1, 512, 0, stream>>>(x, seg, ap, b_in, b_a, wfH, Ag, Hg, Hi, out);
}